// Round 6
// baseline (64562.433 us; speedup 1.0000x reference)
//
#include <hip/hip_runtime.h>
#include <hip/hip_bf16.h>
#include <stdint.h>

#define T_STEPS 8192
#define NX 1024
#define NU 512
#define NY 128
#define HID 4096

#define SEQ_WGS 256
#define SEQ_BLK 512
#define RING 128          // tagged-row ring depth (128 x 16 KB = 2 MB, MALL-resident)

typedef __attribute__((ext_vector_type(8))) short bf16x8;
typedef __attribute__((ext_vector_type(4))) float f32x4;
typedef __attribute__((ext_vector_type(2))) short s16x2;

__device__ __forceinline__ float bf2f(ushort u) {
  union { uint32_t i; float f; } v; v.i = ((uint32_t)u) << 16; return v.f;
}
__device__ __forceinline__ ushort f2bf(float f) {
  union { float f; uint32_t i; } v; v.f = f;
  uint32_t r = v.i + 0x7fffu + ((v.i >> 16) & 1u);
  return (ushort)(r >> 16);
}
__device__ __forceinline__ float lof(uint32_t u) {
  union { uint32_t i; float f; } v; v.i = u << 16; return v.f;
}
__device__ __forceinline__ float hif(uint32_t u) {
  union { uint32_t i; float f; } v; v.i = u & 0xffff0000u; return v.f;
}

// bf16-pair dot with f32 accumulate: acc += h.lo*m.lo + h.hi*m.hi
__device__ __forceinline__ float dot2bf(uint32_t h, uint32_t m, float acc) {
#if __has_builtin(__builtin_amdgcn_fdot2_f32_bf16)
  return __builtin_amdgcn_fdot2_f32_bf16(__builtin_bit_cast(s16x2, h),
                                         __builtin_bit_cast(s16x2, m), acc, false);
#else
  acc = fmaf(lof(h), lof(m), acc);
  return fmaf(hif(h), hif(m), acc);
#endif
}

// fast tanh for the critical path: 1 - 2/(e^{2x}+1) via v_exp_f32 + v_rcp_f32.
// |err| ~1e-6 relative — invisible at bf16. Clamp avoids inf/inf.
__device__ __forceinline__ float fast_tanh(float x) {
  float cx = fminf(fmaxf(x, -15.f), 15.f);
  // e^{2x} = 2^{x * 2*log2(e)}
  float e = __builtin_amdgcn_exp2f(cx * 2.8853900817779268f);
  return 1.f - 2.f * __builtin_amdgcn_rcpf(e + 1.f);
}

// spin-fix a stale tagged word via cache-bypassing atomic loads
__device__ __forceinline__ void fixw(uint32_t& x, uint32_t* wp, uint32_t tg) {
  while ((x & 0xffffu) != tg)
    x = __hip_atomic_load(wp, __ATOMIC_RELAXED, __HIP_MEMORY_SCOPE_AGENT);
}

// two cache-bypassing 16B loads (normal VMEM path, coherent at MALL)
__device__ __forceinline__ void load2_b128_bypass(const uint32_t* p0, uint4& r0, uint4& r1) {
  asm volatile("global_load_dwordx4 %0, %2, off sc0 sc1\n\t"
               "global_load_dwordx4 %1, %3, off sc0 sc1\n\t"
               "s_waitcnt vmcnt(0)"
               : "=&v"(r0), "=&v"(r1)
               : "v"(p0), "v"(p0 + 4)
               : "memory");
}

// ---------------- small utility kernels ----------------

__global__ void cvt_bf16_kernel(const float* __restrict__ in, ushort* __restrict__ out, int n) {
  int i = blockIdx.x * blockDim.x + threadIdx.x;
  int stride = gridDim.x * blockDim.x;
  for (; i < n; i += stride) out[i] = f2bf(in[i]);
}

// out[C][R] = (bf16) in[R][C]
__global__ void transpose_cvt_kernel(const float* __restrict__ in, ushort* __restrict__ out,
                                     int R, int C) {
  __shared__ float tile[32][33];
  int bx = blockIdx.x, by = blockIdx.y;
  int tx = threadIdx.x, ty = threadIdx.y;  // 32 x 8
#pragma unroll
  for (int yy = 0; yy < 4; ++yy) {
    long r = (long)by * 32 + ty + yy * 8;
    long c = (long)bx * 32 + tx;
    tile[ty + yy * 8][tx] = in[r * C + c];
  }
  __syncthreads();
#pragma unroll
  for (int yy = 0; yy < 4; ++yy) {
    long c = (long)bx * 32 + ty + yy * 8;  // out row
    long r = (long)by * 32 + tx;           // out col
    out[c * R + r] = f2bf(tile[tx][ty + yy * 8]);
  }
}

// biasDH[j] = f_b1[j] + sum_k f_b2[k] * f_w1[k][j]
__global__ void bias_dh_kernel(const float* __restrict__ fw1, const float* __restrict__ fb1,
                               const float* __restrict__ fb2, float* __restrict__ biasDH) {
  int j = blockIdx.x * blockDim.x + threadIdx.x;
  float s = fb1[j];
  for (int k = 0; k < NX; ++k) s += fb2[k] * fw1[(long)k * HID + j];
  biasDH[j] = s;
}

// z_0[j] = f_b1[j] + u0 @ W1u[:,j] + x0 @ W1x[:,j]; h_0 = tanh(z_0)
// Publish h_0 into DH row 0 and tagged ring slot 0 (tag = 0).
__global__ void fixup_row0_kernel(const float* __restrict__ fw1, const float* __restrict__ fb1,
                                  const float* __restrict__ u, const float* __restrict__ x0,
                                  ushort* __restrict__ DH, uint32_t* __restrict__ HTAG) {
  int j = blockIdx.x * blockDim.x + threadIdx.x;
  float s = fb1[j];
  for (int k = 0; k < NU; ++k) s += u[k] * fw1[(long)(NX + k) * HID + j];
  for (int k = 0; k < NX; ++k) s += x0[k] * fw1[(long)k * HID + j];
  float h = tanhf(s);
  ushort hb = f2bf(h);
  DH[j] = hb;
  HTAG[j] = ((uint32_t)hb << 16);  // tag = 0
}

__global__ void x0_row_kernel(const float* __restrict__ x0, ushort* __restrict__ X) {
  int j = blockIdx.x * blockDim.x + threadIdx.x;
  if (j < NX) X[j] = f2bf(x0[j]);
}

// ---------------- generic bf16 MFMA GEMM ----------------
// C[M,N] = act( A[M,K] @ B[K,N] + bias ),  B supplied transposed as BT[N,K].
// flags: 1 = tanh, 2 = fp32 output (else bf16)
#define GBM 128
#define GBN 128
#define GBK 32
#define LDT 40

__global__ __launch_bounds__(256) void gemm_kernel(
    const ushort* __restrict__ A, const ushort* __restrict__ BT,
    void* __restrict__ Cout, const float* __restrict__ bias,
    int M, int N, int K, int flags)
{
  __shared__ ushort Al[GBM * LDT];
  __shared__ ushort Bl[GBN * LDT];
  const int tid = threadIdx.x;
  const int bm = blockIdx.y, bn = blockIdx.x;
  const int wave = tid >> 6, lane = tid & 63;
  const int wr = wave >> 1, wc = wave & 1;
  const int l15 = lane & 15, l4 = lane >> 4;

  f32x4 acc[4][4];
#pragma unroll
  for (int m = 0; m < 4; ++m)
#pragma unroll
    for (int n = 0; n < 4; ++n) acc[m][n] = (f32x4){0.f, 0.f, 0.f, 0.f};

  const int r_t = tid >> 1;
  const int h_t = (tid & 1) * 16;
  const long arow = (long)bm * GBM + r_t;
  const long brow = (long)bn * GBN + r_t;

  for (int k0 = 0; k0 < K; k0 += GBK) {
    uint4 a0 = make_uint4(0,0,0,0), a1 = make_uint4(0,0,0,0);
    if (arow < M) {
      const ushort* p = A + arow * K + k0 + h_t;
      a0 = *(const uint4*)p;
      a1 = *(const uint4*)(p + 8);
    }
    const ushort* q = BT + brow * K + k0 + h_t;
    uint4 b0 = *(const uint4*)q;
    uint4 b1 = *(const uint4*)(q + 8);
    __syncthreads();
    *(uint4*)&Al[r_t * LDT + h_t]     = a0;
    *(uint4*)&Al[r_t * LDT + h_t + 8] = a1;
    *(uint4*)&Bl[r_t * LDT + h_t]     = b0;
    *(uint4*)&Bl[r_t * LDT + h_t + 8] = b1;
    __syncthreads();

    bf16x8 af[4], bfv[4];
#pragma unroll
    for (int m = 0; m < 4; ++m)
      af[m] = *(const bf16x8*)&Al[(wr * 64 + m * 16 + l15) * LDT + l4 * 8];
#pragma unroll
    for (int n = 0; n < 4; ++n)
      bfv[n] = *(const bf16x8*)&Bl[(wc * 64 + n * 16 + l15) * LDT + l4 * 8];
#pragma unroll
    for (int m = 0; m < 4; ++m)
#pragma unroll
      for (int n = 0; n < 4; ++n)
        acc[m][n] = __builtin_amdgcn_mfma_f32_16x16x32_bf16(af[m], bfv[n], acc[m][n], 0, 0, 0);
  }

  const bool f32out = (flags & 2) != 0;
  const bool dotanh = (flags & 1) != 0;
#pragma unroll
  for (int m = 0; m < 4; ++m) {
#pragma unroll
    for (int n = 0; n < 4; ++n) {
#pragma unroll
      for (int j = 0; j < 4; ++j) {
        long grow = (long)bm * GBM + wr * 64 + m * 16 + l4 * 4 + j;
        int  gcol = bn * GBN + wc * 64 + n * 16 + l15;
        if (grow < M) {
          float v = acc[m][n][j];
          if (bias) v += bias[gcol];
          if (dotanh) v = tanhf(v);
          if (f32out) ((float*)Cout)[grow * N + gcol] = v;
          else        ((ushort*)Cout)[grow * N + gcol] = f2bf(v);
        }
      }
    }
  }
}

// ---------------- persistent sequential kernel (direct-poll, chunked, barrier-free) --
// h_{i+1} = tanh(h_i @ M + D[i+1]).
// Ring of RING tagged rows: word = (bf16(h)<<16) | (step & 0xffff).
// Wave j of each WG owns CHUNK j (h-elems [512j,512j+512)) == its m[j] k-slice:
//   - polls chunk j directly with sc0sc1-bypass dwordx4 loads (detect == fetch,
//     one MALL RTT); tag-verified, capped-spin fallback to per-word atomics.
//   - dots its own chunk straight from the polled registers,
//   - stages packed bf16 to double-buffered LDS + release-flag for other waves.
// Other chunks: acquire-spin on LDS flag, ds_read_b128, dot. NO __syncthreads in
// the loop. Overwrite safety (LDS buf parity & ring reuse): publishing h_i
// requires the whole chip consumed h_{i-1}, so step-i staging can never clobber
// data still being read (skew across waves/WGs is bounded by the data flow).
// 0xAA poison tag = 0xAAAA is outside the 0..8190 step-tag range.
__global__ __launch_bounds__(SEQ_BLK, 1) void seq_kernel(
    const ushort* __restrict__ MT, ushort* __restrict__ DH,
    uint32_t* __restrict__ HTAG, int nsteps)
{
  __shared__ ushort hl[2][HID];   // 16 KB double-buffered h staging
  __shared__ int flags[8];        // last staged step per chunk

  const int tid = threadIdx.x;
  const int w = tid >> 6;                        // wave 0..7 == chunk id
  const int lane = tid & 63;
  const int c0 = (blockIdx.x << 4) + (w << 1);   // this wave's first output column

  // M fragments: packed bf16, 2 columns x 8 uint4 = 64 VGPRs.
  // m{A,B}[j] covers k in [512j + 8*lane, 512j + 8*lane + 8).
  uint4 mA[8], mB[8];
  {
    const uint4* rA = (const uint4*)(MT + (size_t)c0 * HID);
    const uint4* rB = (const uint4*)(MT + (size_t)(c0 + 1) * HID);
#pragma unroll
    for (int j = 0; j < 8; ++j) {
      mA[j] = rA[lane + 64 * j];
      mB[j] = rB[lane + 64 * j];
    }
  }

  if (tid < 8) flags[tid] = -1;
  __syncthreads();

  const bool prod = (lane == 0);

  for (int i = 0; i < nsteps; ++i) {
    const uint32_t tg = (uint32_t)i & 0xffffu;
    uint32_t* rowp = HTAG + (size_t)(i & (RING - 1)) * HID;
    const int buf = i & 1;

    // Prefetch D_{i+1} for both columns (own dword; independent load, schedules early).
    float dA = 0.f, dB = 0.f;
    if (prod) {
      uint32_t dw = *(const uint32_t*)(DH + (size_t)(i + 1) * HID + c0);
      dA = lof(dw); dB = hif(dw);
    }

    // ---- poll own chunk directly (detect == fetch, one bypass RTT) ----
    uint32_t* p0 = rowp + 512 * w + 8 * lane;
    uint4 v0, v1;
    {
      int spins = 0;
      for (;;) {
        load2_b128_bypass(p0, v0, v1);
        uint32_t bad = ((v0.x ^ tg) | (v0.y ^ tg) | (v0.z ^ tg) | (v0.w ^ tg) |
                        (v1.x ^ tg) | (v1.y ^ tg) | (v1.z ^ tg) | (v1.w ^ tg)) & 0xffffu;
        if (__all(bad == 0)) break;
        if (__builtin_expect(++spins > (1 << 18), 0)) {
          fixw(v0.x, p0 + 0, tg); fixw(v0.y, p0 + 1, tg);
          fixw(v0.z, p0 + 2, tg); fixw(v0.w, p0 + 3, tg);
          fixw(v1.x, p0 + 4, tg); fixw(v1.y, p0 + 5, tg);
          fixw(v1.z, p0 + 6, tg); fixw(v1.w, p0 + 7, tg);
          break;
        }
        __builtin_amdgcn_s_sleep(1);
      }
    }

    // pack 8 tagged words -> 8 bf16 (one uint4)
    uint4 pk;
    pk.x = (v0.x >> 16) | (v0.y & 0xffff0000u);
    pk.y = (v0.z >> 16) | (v0.w & 0xffff0000u);
    pk.z = (v1.x >> 16) | (v1.y & 0xffff0000u);
    pk.w = (v1.z >> 16) | (v1.w & 0xffff0000u);

    // stage own chunk for the other waves, then release-flag
    *(uint4*)&hl[buf][512 * w + 8 * lane] = pk;
    __hip_atomic_store(&flags[w], i, __ATOMIC_RELEASE, __HIP_MEMORY_SCOPE_WORKGROUP);

    // ---- dot own chunk from registers ----
    float accA = 0.f, accB = 0.f;
    accA = dot2bf(pk.x, mA[w].x, accA);  accB = dot2bf(pk.x, mB[w].x, accB);
    accA = dot2bf(pk.y, mA[w].y, accA);  accB = dot2bf(pk.y, mB[w].y, accB);
    accA = dot2bf(pk.z, mA[w].z, accA);  accB = dot2bf(pk.z, mB[w].z, accB);
    accA = dot2bf(pk.w, mA[w].w, accA);  accB = dot2bf(pk.w, mB[w].w, accB);

    // ---- other chunks as they land (acquire flag -> ds_read -> dot) ----
#pragma unroll
    for (int jj = 1; jj < 8; ++jj) {
      const int j = (w + jj) & 7;
      while (__hip_atomic_load(&flags[j], __ATOMIC_ACQUIRE,
                               __HIP_MEMORY_SCOPE_WORKGROUP) < i) { }
      uint4 hv = *(const uint4*)&hl[buf][512 * j + 8 * lane];
      accA = dot2bf(hv.x, mA[j].x, accA);  accB = dot2bf(hv.x, mB[j].x, accB);
      accA = dot2bf(hv.y, mA[j].y, accA);  accB = dot2bf(hv.y, mB[j].y, accB);
      accA = dot2bf(hv.z, mA[j].z, accA);  accB = dot2bf(hv.z, mB[j].z, accB);
      accA = dot2bf(hv.w, mA[j].w, accA);  accB = dot2bf(hv.w, mB[j].w, accB);
    }

    // dual reduce: fold halves, butterfly within halves, fetch B total to lane0
    accA += __shfl_xor(accA, 32, 64);
    accB += __shfl_xor(accB, 32, 64);
    float y = (lane < 32) ? accA : accB;
#pragma unroll
    for (int off = 16; off >= 1; off >>= 1)
      y += __shfl_xor(y, off, 64);
    float totB = __shfl(y, 32, 64);

    if (prod) {
      ushort ha = f2bf(fast_tanh(y + dA));
      ushort hb = f2bf(fast_tanh(totB + dB));
      uint32_t tg1 = (uint32_t)(i + 1) & 0xffffu;
      unsigned long long word =
          ((unsigned long long)(((uint32_t)hb << 16) | tg1) << 32) |
          (unsigned long long)(((uint32_t)ha << 16) | tg1);
      unsigned long long* dst =
          (unsigned long long*)(HTAG + (size_t)((i + 1) & (RING - 1)) * HID) + (c0 >> 1);
      __hip_atomic_store(dst, word, __ATOMIC_RELAXED, __HIP_MEMORY_SCOPE_AGENT);
      *(uint32_t*)(DH + (size_t)(i + 1) * HID + c0) = (uint32_t)ha | ((uint32_t)hb << 16);
    }
  }
}

// ---------------- launch ----------------

extern "C" void kernel_launch(void* const* d_in, const int* in_sizes, int n_in,
                              void* d_out, int out_size, void* d_ws, size_t ws_size,
                              hipStream_t stream) {
  const float* x0  = (const float*)d_in[0];
  const float* u   = (const float*)d_in[1];
  const float* fw1 = (const float*)d_in[2];
  const float* fb1 = (const float*)d_in[3];
  const float* fw2 = (const float*)d_in[4];
  const float* fb2 = (const float*)d_in[5];
  const float* gw1 = (const float*)d_in[6];
  const float* gb1 = (const float*)d_in[7];
  const float* gw2 = (const float*)d_in[8];
  const float* gb2 = (const float*)d_in[9];
  float* out = (float*)d_out;

  char* ws = (char*)d_ws;
  size_t off = 0;
  auto alloc = [&](size_t bytes) -> char* {
    char* p = ws + off; off += (bytes + 255) & ~(size_t)255; return p;
  };
  ushort* MT     = (ushort*)alloc((size_t)HID * HID * 2);
  ushort* DH     = (ushort*)alloc((size_t)T_STEPS * HID * 2);
  ushort* X      = (ushort*)alloc((size_t)T_STEPS * NX * 2);
  ushort* W1xT   = (ushort*)alloc((size_t)HID * NX * 2);
  ushort* W1uT   = (ushort*)alloc((size_t)HID * NU * 2);
  ushort* W2bf   = (ushort*)alloc((size_t)HID * NX * 2);
  ushort* W2T    = (ushort*)alloc((size_t)NX * HID * 2);
  ushort* Gw1T   = (ushort*)alloc((size_t)HID * NX * 2);
  ushort* Gw2T   = (ushort*)alloc((size_t)NY * HID * 2);
  ushort* Ubf    = (ushort*)alloc((size_t)T_STEPS * NU * 2);
  float*  biasDH = (float*)alloc((size_t)HID * 4);
  uint32_t* HTAG = (uint32_t*)alloc((size_t)RING * HID * 4);
  if (off > ws_size) return;  // workspace too small; bail

  cvt_bf16_kernel<<<2048, 256, 0, stream>>>(u, Ubf, T_STEPS * NU);
  cvt_bf16_kernel<<<2048, 256, 0, stream>>>(fw2, W2bf, HID * NX);
  transpose_cvt_kernel<<<dim3(HID/32, NX/32), dim3(32, 8), 0, stream>>>(fw1, W1xT, NX, HID);
  transpose_cvt_kernel<<<dim3(HID/32, NU/32), dim3(32, 8), 0, stream>>>(fw1 + (size_t)NX * HID, W1uT, NU, HID);
  transpose_cvt_kernel<<<dim3(NX/32, HID/32), dim3(32, 8), 0, stream>>>(fw2, W2T, HID, NX);
  transpose_cvt_kernel<<<dim3(HID/32, NX/32), dim3(32, 8), 0, stream>>>(gw1, Gw1T, NX, HID);
  transpose_cvt_kernel<<<dim3(NY/32, HID/32), dim3(32, 8), 0, stream>>>(gw2, Gw2T, HID, NY);
  bias_dh_kernel<<<HID/256, 256, 0, stream>>>(fw1, fb1, fb2, biasDH);

  // MT[j][k] = M[k][j] = sum_p W2[k][p] * W1x[p][j]
  gemm_kernel<<<dim3(HID/128, HID/128), 256, 0, stream>>>(W1xT, W2bf, MT, nullptr, HID, HID, NX, 0);
  // DH = Ubf @ W1u + (b1 + b2@W1x)
  gemm_kernel<<<dim3(HID/128, T_STEPS/128), 256, 0, stream>>>(Ubf, W1uT, DH, biasDH, T_STEPS, HID, NU, 0);
  // h_0 into DH row 0 + tagged ring slot 0
  fixup_row0_kernel<<<HID/256, 256, 0, stream>>>(fw1, fb1, u, x0, DH, HTAG);

  // sequential recurrence: h_{i+1} = tanh(h_i @ M + D[i+1]), i = 0..8189
  {
    int nsteps = T_STEPS - 2;  // produce h_1 .. h_8190
    void* MT_p = (void*)MT; void* DH_p = (void*)DH; void* ht_p = (void*)HTAG;
    void* args[] = { &MT_p, &DH_p, &ht_p, &nsteps };
    hipError_t e = hipLaunchCooperativeKernel((const void*)seq_kernel, dim3(SEQ_WGS),
                                              dim3(SEQ_BLK), args, 0, stream);
    if (e != hipSuccess) {
      (void)hipGetLastError();
      seq_kernel<<<SEQ_WGS, SEQ_BLK, 0, stream>>>(MT, DH, HTAG, nsteps);
    }
  }

  x0_row_kernel<<<NX/256, 256, 0, stream>>>(x0, X);
  // X[1..8191] = H[0..8190] @ W2 + b2
  gemm_kernel<<<dim3(NX/128, T_STEPS/128), 256, 0, stream>>>(DH, W2T, X + NX, fb2, T_STEPS - 1, NX, HID, 0);
  // G = tanh(X @ g_w1 + g_b1) -> reuse DH buffer
  gemm_kernel<<<dim3(HID/128, T_STEPS/128), 256, 0, stream>>>(X, Gw1T, DH, gb1, T_STEPS, HID, NX, 1);
  // Y = G @ g_w2 + g_b2 -> fp32 out
  gemm_kernel<<<dim3(NY/128, T_STEPS/128), 256, 0, stream>>>(DH, Gw2T, out, gb2, T_STEPS, NY, HID, 2);
}

// Round 7
// 63115.033 us; speedup vs baseline: 1.0229x; 1.0229x over previous
//
#include <hip/hip_runtime.h>
#include <hip/hip_bf16.h>
#include <stdint.h>

#define T_STEPS 8192
#define NX 1024
#define NU 512
#define NY 128
#define HID 4096

#define SEQ_WGS 256
#define SEQ_BLK 512
#define RING 128          // tagged-row ring depth (128 x 16 KB = 2 MB)

typedef __attribute__((ext_vector_type(8))) short bf16x8;
typedef __attribute__((ext_vector_type(4))) float f32x4;
typedef __attribute__((ext_vector_type(2))) short s16x2;

__device__ __forceinline__ float bf2f(ushort u) {
  union { uint32_t i; float f; } v; v.i = ((uint32_t)u) << 16; return v.f;
}
__device__ __forceinline__ ushort f2bf(float f) {
  union { float f; uint32_t i; } v; v.f = f;
  uint32_t r = v.i + 0x7fffu + ((v.i >> 16) & 1u);
  return (ushort)(r >> 16);
}
__device__ __forceinline__ float lof(uint32_t u) {
  union { uint32_t i; float f; } v; v.i = u << 16; return v.f;
}
__device__ __forceinline__ float hif(uint32_t u) {
  union { uint32_t i; float f; } v; v.i = u & 0xffff0000u; return v.f;
}

// bf16-pair dot with f32 accumulate: acc += h.lo*m.lo + h.hi*m.hi
__device__ __forceinline__ float dot2bf(uint32_t h, uint32_t m, float acc) {
#if __has_builtin(__builtin_amdgcn_fdot2_f32_bf16)
  return __builtin_amdgcn_fdot2_f32_bf16(__builtin_bit_cast(s16x2, h),
                                         __builtin_bit_cast(s16x2, m), acc, false);
#else
  acc = fmaf(lof(h), lof(m), acc);
  return fmaf(hif(h), hif(m), acc);
#endif
}

// fast tanh: 1 - 2/(e^{2x}+1) via v_exp_f32 + v_rcp_f32; |rel err| ~1e-6.
__device__ __forceinline__ float fast_tanh(float x) {
  float cx = fminf(fmaxf(x, -15.f), 15.f);
  float e = __builtin_amdgcn_exp2f(cx * 2.8853900817779268f);  // e^{2x}
  return 1.f - 2.f * __builtin_amdgcn_rcpf(e + 1.f);
}

// spin-fix a stale tagged word via cache-bypassing atomic loads (correctness net)
__device__ __forceinline__ void fixw(uint32_t& x, uint32_t* wp, uint32_t tg) {
  while ((x & 0xffffu) != tg)
    x = __hip_atomic_load(wp, __ATOMIC_RELAXED, __HIP_MEMORY_SCOPE_AGENT);
}

// ---------------- small utility kernels ----------------

__global__ void cvt_bf16_kernel(const float* __restrict__ in, ushort* __restrict__ out, int n) {
  int i = blockIdx.x * blockDim.x + threadIdx.x;
  int stride = gridDim.x * blockDim.x;
  for (; i < n; i += stride) out[i] = f2bf(in[i]);
}

// out[C][R] = (bf16) in[R][C]
__global__ void transpose_cvt_kernel(const float* __restrict__ in, ushort* __restrict__ out,
                                     int R, int C) {
  __shared__ float tile[32][33];
  int bx = blockIdx.x, by = blockIdx.y;
  int tx = threadIdx.x, ty = threadIdx.y;  // 32 x 8
#pragma unroll
  for (int yy = 0; yy < 4; ++yy) {
    long r = (long)by * 32 + ty + yy * 8;
    long c = (long)bx * 32 + tx;
    tile[ty + yy * 8][tx] = in[r * C + c];
  }
  __syncthreads();
#pragma unroll
  for (int yy = 0; yy < 4; ++yy) {
    long c = (long)bx * 32 + ty + yy * 8;  // out row
    long r = (long)by * 32 + tx;           // out col
    out[c * R + r] = f2bf(tile[tx][ty + yy * 8]);
  }
}

// biasDH[j] = f_b1[j] + sum_k f_b2[k] * f_w1[k][j]
__global__ void bias_dh_kernel(const float* __restrict__ fw1, const float* __restrict__ fb1,
                               const float* __restrict__ fb2, float* __restrict__ biasDH) {
  int j = blockIdx.x * blockDim.x + threadIdx.x;
  float s = fb1[j];
  for (int k = 0; k < NX; ++k) s += fb2[k] * fw1[(long)k * HID + j];
  biasDH[j] = s;
}

// z_0[j] = f_b1[j] + u0 @ W1u[:,j] + x0 @ W1x[:,j]; h_0 = tanh(z_0)
__global__ void fixup_row0_kernel(const float* __restrict__ fw1, const float* __restrict__ fb1,
                                  const float* __restrict__ u, const float* __restrict__ x0,
                                  ushort* __restrict__ DH, uint32_t* __restrict__ HTAG) {
  int j = blockIdx.x * blockDim.x + threadIdx.x;
  float s = fb1[j];
  for (int k = 0; k < NU; ++k) s += u[k] * fw1[(long)(NX + k) * HID + j];
  for (int k = 0; k < NX; ++k) s += x0[k] * fw1[(long)k * HID + j];
  float h = tanhf(s);
  ushort hb = f2bf(h);
  DH[j] = hb;
  HTAG[j] = ((uint32_t)hb << 16);  // tag = 0
}

__global__ void x0_row_kernel(const float* __restrict__ x0, ushort* __restrict__ X) {
  int j = blockIdx.x * blockDim.x + threadIdx.x;
  if (j < NX) X[j] = f2bf(x0[j]);
}

// ---------------- generic bf16 MFMA GEMM ----------------
#define GBM 128
#define GBN 128
#define GBK 32
#define LDT 40

__global__ __launch_bounds__(256) void gemm_kernel(
    const ushort* __restrict__ A, const ushort* __restrict__ BT,
    void* __restrict__ Cout, const float* __restrict__ bias,
    int M, int N, int K, int flags)
{
  __shared__ ushort Al[GBM * LDT];
  __shared__ ushort Bl[GBN * LDT];
  const int tid = threadIdx.x;
  const int bm = blockIdx.y, bn = blockIdx.x;
  const int wave = tid >> 6, lane = tid & 63;
  const int wr = wave >> 1, wc = wave & 1;
  const int l15 = lane & 15, l4 = lane >> 4;

  f32x4 acc[4][4];
#pragma unroll
  for (int m = 0; m < 4; ++m)
#pragma unroll
    for (int n = 0; n < 4; ++n) acc[m][n] = (f32x4){0.f, 0.f, 0.f, 0.f};

  const int r_t = tid >> 1;
  const int h_t = (tid & 1) * 16;
  const long arow = (long)bm * GBM + r_t;
  const long brow = (long)bn * GBN + r_t;

  for (int k0 = 0; k0 < K; k0 += GBK) {
    uint4 a0 = make_uint4(0,0,0,0), a1 = make_uint4(0,0,0,0);
    if (arow < M) {
      const ushort* p = A + arow * K + k0 + h_t;
      a0 = *(const uint4*)p;
      a1 = *(const uint4*)(p + 8);
    }
    const ushort* q = BT + brow * K + k0 + h_t;
    uint4 b0 = *(const uint4*)q;
    uint4 b1 = *(const uint4*)(q + 8);
    __syncthreads();
    *(uint4*)&Al[r_t * LDT + h_t]     = a0;
    *(uint4*)&Al[r_t * LDT + h_t + 8] = a1;
    *(uint4*)&Bl[r_t * LDT + h_t]     = b0;
    *(uint4*)&Bl[r_t * LDT + h_t + 8] = b1;
    __syncthreads();

    bf16x8 af[4], bfv[4];
#pragma unroll
    for (int m = 0; m < 4; ++m)
      af[m] = *(const bf16x8*)&Al[(wr * 64 + m * 16 + l15) * LDT + l4 * 8];
#pragma unroll
    for (int n = 0; n < 4; ++n)
      bfv[n] = *(const bf16x8*)&Bl[(wc * 64 + n * 16 + l15) * LDT + l4 * 8];
#pragma unroll
    for (int m = 0; m < 4; ++m)
#pragma unroll
      for (int n = 0; n < 4; ++n)
        acc[m][n] = __builtin_amdgcn_mfma_f32_16x16x32_bf16(af[m], bfv[n], acc[m][n], 0, 0, 0);
  }

  const bool f32out = (flags & 2) != 0;
  const bool dotanh = (flags & 1) != 0;
#pragma unroll
  for (int m = 0; m < 4; ++m) {
#pragma unroll
    for (int n = 0; n < 4; ++n) {
#pragma unroll
      for (int j = 0; j < 4; ++j) {
        long grow = (long)bm * GBM + wr * 64 + m * 16 + l4 * 4 + j;
        int  gcol = bn * GBN + wc * 64 + n * 16 + l15;
        if (grow < M) {
          float v = acc[m][n][j];
          if (bias) v += bias[gcol];
          if (dotanh) v = tanhf(v);
          if (f32out) ((float*)Cout)[grow * N + gcol] = v;
          else        ((ushort*)Cout)[grow * N + gcol] = f2bf(v);
        }
      }
    }
  }
}

// ---------------- persistent sequential kernel (chunked sentinel + cached bulk) ------
// h_{i+1} = tanh(h_i @ M + D[i+1]).   Ring of RING tagged rows: word =
// (bf16(h)<<16) | (step & 0xffff).  Producers: one u64 agent store per wave.
//
// Wave w of each WG owns CHUNK w (h elems [512w, 512w+512)):
//   1. lanes<32 poll the 32 producer-WG sentinels of chunk w (agent atomics +
//      s_sleep) — notification channel, tiny traffic.
//   2. fetch the 2KB chunk with PLAIN CACHED dwordx4 loads (each ring address
//      is cold — read once per 128 steps — and the XCD's 32 co-located WGs
//      share the L2 copy: one MALL fetch per line per XCD). Tag-verify; any
//      stale word is re-fetched via agent atomics (fixw) — correctness never
//      depends on cache luck. 0xAA poison tag (0xAAAA) can't match any step.
//   3. stage chunk to double-buffered LDS, release-flag; dot own chunk from
//      registers; consume sibling chunks via acquire flags. NO __syncthreads.
// Safety: wave/WG skew is bounded to 1 step by the dataflow (publishing h_{i+1}
// requires consuming all of h_i), so LDS parity-2 and ring-128 reuse are safe.
__global__ __launch_bounds__(SEQ_BLK, 1) void seq_kernel(
    const ushort* __restrict__ MT, ushort* __restrict__ DH,
    uint32_t* __restrict__ HTAG, int nsteps)
{
  __shared__ ushort hl[2][HID];   // 16 KB double-buffered h staging
  __shared__ int flags[8];        // last staged step per chunk

  const int tid = threadIdx.x;
  const int w = tid >> 6;                        // wave 0..7 == chunk id
  const int lane = tid & 63;
  const int c0 = (blockIdx.x << 4) + (w << 1);   // this wave's first output column

  // M fragments: packed bf16, 2 columns x 8 uint4 = 64 VGPRs.
  // m{A,B}[j] covers k in [512j + 8*lane, 512j + 8*lane + 8).
  uint4 mA[8], mB[8];
  {
    const uint4* rA = (const uint4*)(MT + (size_t)c0 * HID);
    const uint4* rB = (const uint4*)(MT + (size_t)(c0 + 1) * HID);
#pragma unroll
    for (int j = 0; j < 8; ++j) {
      mA[j] = rA[lane + 64 * j];
      mB[j] = rB[lane + 64 * j];
    }
  }

  if (tid < 8) flags[tid] = -1;
  __syncthreads();

  const bool prod = (lane == 0);

  for (int i = 0; i < nsteps; ++i) {
    const uint32_t tg = (uint32_t)i & 0xffffu;
    uint32_t* rowp = HTAG + (size_t)(i & (RING - 1)) * HID;
    const int buf = i & 1;

    // Prefetch D_{i+1} for both columns (own dword).
    float dA = 0.f, dB = 0.f;
    if (prod) {
      uint32_t dw = *(const uint32_t*)(DH + (size_t)(i + 1) * HID + c0);
      dA = lof(dw); dB = hif(dw);
    }

    // ---- 1. sentinel poll: chunk w is produced by WGs [32w, 32w+32) ----
    if (lane < 32) {
      uint32_t* sp = rowp + 16 * ((w << 5) + lane) + 15;
      while ((__hip_atomic_load(sp, __ATOMIC_RELAXED, __HIP_MEMORY_SCOPE_AGENT)
              & 0xffffu) != tg)
        __builtin_amdgcn_s_sleep(1);
    }
    asm volatile("" ::: "memory");   // compiler barrier: keep loads below the spin

    // ---- 2. cached bulk fetch of own chunk (32B/lane) + verify ----
    uint4 v0, v1;
    {
      const uint4* cp = (const uint4*)(rowp + 512 * w);
      v0 = cp[2 * lane];
      v1 = cp[2 * lane + 1];
      uint32_t bad = ((v0.x ^ tg) | (v0.y ^ tg) | (v0.z ^ tg) | (v0.w ^ tg) |
                      (v1.x ^ tg) | (v1.y ^ tg) | (v1.z ^ tg) | (v1.w ^ tg)) & 0xffffu;
      if (__builtin_expect(bad != 0, 0)) {
        uint32_t* wp = rowp + 512 * w + 8 * lane;
        fixw(v0.x, wp + 0, tg); fixw(v0.y, wp + 1, tg);
        fixw(v0.z, wp + 2, tg); fixw(v0.w, wp + 3, tg);
        fixw(v1.x, wp + 4, tg); fixw(v1.y, wp + 5, tg);
        fixw(v1.z, wp + 6, tg); fixw(v1.w, wp + 7, tg);
      }
    }

    // pack 8 tagged words -> 8 bf16 (one uint4)
    uint4 pk;
    pk.x = (v0.x >> 16) | (v0.y & 0xffff0000u);
    pk.y = (v0.z >> 16) | (v0.w & 0xffff0000u);
    pk.z = (v1.x >> 16) | (v1.y & 0xffff0000u);
    pk.w = (v1.z >> 16) | (v1.w & 0xffff0000u);

    // ---- 3. stage own chunk + release; dot own chunk from registers ----
    *(uint4*)&hl[buf][512 * w + 8 * lane] = pk;
    __hip_atomic_store(&flags[w], i, __ATOMIC_RELEASE, __HIP_MEMORY_SCOPE_WORKGROUP);

    float accA = 0.f, accB = 0.f;
    accA = dot2bf(pk.x, mA[w].x, accA);  accB = dot2bf(pk.x, mB[w].x, accB);
    accA = dot2bf(pk.y, mA[w].y, accA);  accB = dot2bf(pk.y, mB[w].y, accB);
    accA = dot2bf(pk.z, mA[w].z, accA);  accB = dot2bf(pk.z, mB[w].z, accB);
    accA = dot2bf(pk.w, mA[w].w, accA);  accB = dot2bf(pk.w, mB[w].w, accB);

    // ---- sibling chunks as they land (acquire flag -> ds_read -> dot) ----
#pragma unroll
    for (int jj = 1; jj < 8; ++jj) {
      const int j = (w + jj) & 7;
      while (__hip_atomic_load(&flags[j], __ATOMIC_ACQUIRE,
                               __HIP_MEMORY_SCOPE_WORKGROUP) < i) { }
      uint4 hv = *(const uint4*)&hl[buf][512 * j + 8 * lane];
      accA = dot2bf(hv.x, mA[j].x, accA);  accB = dot2bf(hv.x, mB[j].x, accB);
      accA = dot2bf(hv.y, mA[j].y, accA);  accB = dot2bf(hv.y, mB[j].y, accB);
      accA = dot2bf(hv.z, mA[j].z, accA);  accB = dot2bf(hv.z, mB[j].z, accB);
      accA = dot2bf(hv.w, mA[j].w, accA);  accB = dot2bf(hv.w, mB[j].w, accB);
    }

    // dual reduce: fold halves, butterfly within halves, fetch B total to lane0
    accA += __shfl_xor(accA, 32, 64);
    accB += __shfl_xor(accB, 32, 64);
    float y = (lane < 32) ? accA : accB;
#pragma unroll
    for (int off = 16; off >= 1; off >>= 1)
      y += __shfl_xor(y, off, 64);
    float totB = __shfl(y, 32, 64);

    if (prod) {
      ushort ha = f2bf(fast_tanh(y + dA));
      ushort hb = f2bf(fast_tanh(totB + dB));
      uint32_t tg1 = (uint32_t)(i + 1) & 0xffffu;
      unsigned long long word =
          ((unsigned long long)(((uint32_t)hb << 16) | tg1) << 32) |
          (unsigned long long)(((uint32_t)ha << 16) | tg1);
      unsigned long long* dst =
          (unsigned long long*)(HTAG + (size_t)((i + 1) & (RING - 1)) * HID) + (c0 >> 1);
      __hip_atomic_store(dst, word, __ATOMIC_RELAXED, __HIP_MEMORY_SCOPE_AGENT);
      *(uint32_t*)(DH + (size_t)(i + 1) * HID + c0) = (uint32_t)ha | ((uint32_t)hb << 16);
    }
  }
}

// ---------------- launch ----------------

extern "C" void kernel_launch(void* const* d_in, const int* in_sizes, int n_in,
                              void* d_out, int out_size, void* d_ws, size_t ws_size,
                              hipStream_t stream) {
  const float* x0  = (const float*)d_in[0];
  const float* u   = (const float*)d_in[1];
  const float* fw1 = (const float*)d_in[2];
  const float* fb1 = (const float*)d_in[3];
  const float* fw2 = (const float*)d_in[4];
  const float* fb2 = (const float*)d_in[5];
  const float* gw1 = (const float*)d_in[6];
  const float* gb1 = (const float*)d_in[7];
  const float* gw2 = (const float*)d_in[8];
  const float* gb2 = (const float*)d_in[9];
  float* out = (float*)d_out;

  char* ws = (char*)d_ws;
  size_t off = 0;
  auto alloc = [&](size_t bytes) -> char* {
    char* p = ws + off; off += (bytes + 255) & ~(size_t)255; return p;
  };
  ushort* MT     = (ushort*)alloc((size_t)HID * HID * 2);
  ushort* DH     = (ushort*)alloc((size_t)T_STEPS * HID * 2);
  ushort* X      = (ushort*)alloc((size_t)T_STEPS * NX * 2);
  ushort* W1xT   = (ushort*)alloc((size_t)HID * NX * 2);
  ushort* W1uT   = (ushort*)alloc((size_t)HID * NU * 2);
  ushort* W2bf   = (ushort*)alloc((size_t)HID * NX * 2);
  ushort* W2T    = (ushort*)alloc((size_t)NX * HID * 2);
  ushort* Gw1T   = (ushort*)alloc((size_t)HID * NX * 2);
  ushort* Gw2T   = (ushort*)alloc((size_t)NY * HID * 2);
  ushort* Ubf    = (ushort*)alloc((size_t)T_STEPS * NU * 2);
  float*  biasDH = (float*)alloc((size_t)HID * 4);
  uint32_t* HTAG = (uint32_t*)alloc((size_t)RING * HID * 4);
  if (off > ws_size) return;  // workspace too small; bail

  cvt_bf16_kernel<<<2048, 256, 0, stream>>>(u, Ubf, T_STEPS * NU);
  cvt_bf16_kernel<<<2048, 256, 0, stream>>>(fw2, W2bf, HID * NX);
  transpose_cvt_kernel<<<dim3(HID/32, NX/32), dim3(32, 8), 0, stream>>>(fw1, W1xT, NX, HID);
  transpose_cvt_kernel<<<dim3(HID/32, NU/32), dim3(32, 8), 0, stream>>>(fw1 + (size_t)NX * HID, W1uT, NU, HID);
  transpose_cvt_kernel<<<dim3(NX/32, HID/32), dim3(32, 8), 0, stream>>>(fw2, W2T, HID, NX);
  transpose_cvt_kernel<<<dim3(HID/32, NX/32), dim3(32, 8), 0, stream>>>(gw1, Gw1T, NX, HID);
  transpose_cvt_kernel<<<dim3(NY/32, HID/32), dim3(32, 8), 0, stream>>>(gw2, Gw2T, HID, NY);
  bias_dh_kernel<<<HID/256, 256, 0, stream>>>(fw1, fb1, fb2, biasDH);

  // MT[j][k] = M[k][j] = sum_p W2[k][p] * W1x[p][j]
  gemm_kernel<<<dim3(HID/128, HID/128), 256, 0, stream>>>(W1xT, W2bf, MT, nullptr, HID, HID, NX, 0);
  // DH = Ubf @ W1u + (b1 + b2@W1x)
  gemm_kernel<<<dim3(HID/128, T_STEPS/128), 256, 0, stream>>>(Ubf, W1uT, DH, biasDH, T_STEPS, HID, NU, 0);
  // h_0 into DH row 0 + tagged ring slot 0
  fixup_row0_kernel<<<HID/256, 256, 0, stream>>>(fw1, fb1, u, x0, DH, HTAG);

  // sequential recurrence: h_{i+1} = tanh(h_i @ M + D[i+1]), i = 0..8189
  {
    int nsteps = T_STEPS - 2;  // produce h_1 .. h_8190
    void* MT_p = (void*)MT; void* DH_p = (void*)DH; void* ht_p = (void*)HTAG;
    void* args[] = { &MT_p, &DH_p, &ht_p, &nsteps };
    hipError_t e = hipLaunchCooperativeKernel((const void*)seq_kernel, dim3(SEQ_WGS),
                                              dim3(SEQ_BLK), args, 0, stream);
    if (e != hipSuccess) {
      (void)hipGetLastError();
      seq_kernel<<<SEQ_WGS, SEQ_BLK, 0, stream>>>(MT, DH, HTAG, nsteps);
    }
  }

  x0_row_kernel<<<NX/256, 256, 0, stream>>>(x0, X);
  // X[1..8191] = H[0..8190] @ W2 + b2
  gemm_kernel<<<dim3(NX/128, T_STEPS/128), 256, 0, stream>>>(DH, W2T, X + NX, fb2, T_STEPS - 1, NX, HID, 0);
  // G = tanh(X @ g_w1 + g_b1) -> reuse DH buffer
  gemm_kernel<<<dim3(HID/128, T_STEPS/128), 256, 0, stream>>>(X, Gw1T, DH, gb1, T_STEPS, HID, NX, 1);
  // Y = G @ g_w2 + g_b2 -> fp32 out
  gemm_kernel<<<dim3(NY/128, T_STEPS/128), 256, 0, stream>>>(DH, Gw2T, out, gb2, T_STEPS, NY, HID, 2);
}

// Round 8
// 29580.652 us; speedup vs baseline: 2.1826x; 2.1337x over previous
//
#include <hip/hip_runtime.h>
#include <hip/hip_bf16.h>
#include <stdint.h>

#define T_STEPS 8192
#define NX 1024
#define NU 512
#define NY 128
#define HID 4096

#define SEQ_WGS 256
#define SEQ_BLK 512
#define RING 256          // tagged-row ring depth (256 x 16 KB = 4 MB)

typedef __attribute__((ext_vector_type(8))) short bf16x8;
typedef __attribute__((ext_vector_type(4))) float f32x4;
typedef __attribute__((ext_vector_type(2))) short s16x2;

__device__ __forceinline__ float bf2f(ushort u) {
  union { uint32_t i; float f; } v; v.i = ((uint32_t)u) << 16; return v.f;
}
__device__ __forceinline__ ushort f2bf(float f) {
  union { float f; uint32_t i; } v; v.f = f;
  uint32_t r = v.i + 0x7fffu + ((v.i >> 16) & 1u);
  return (ushort)(r >> 16);
}
__device__ __forceinline__ float lof(uint32_t u) {
  union { uint32_t i; float f; } v; v.i = u << 16; return v.f;
}
__device__ __forceinline__ float hif(uint32_t u) {
  union { uint32_t i; float f; } v; v.i = u & 0xffff0000u; return v.f;
}

// bf16-pair dot with f32 accumulate: acc += h.lo*m.lo + h.hi*m.hi
__device__ __forceinline__ float dot2bf(uint32_t h, uint32_t m, float acc) {
#if __has_builtin(__builtin_amdgcn_fdot2_f32_bf16)
  return __builtin_amdgcn_fdot2_f32_bf16(__builtin_bit_cast(s16x2, h),
                                         __builtin_bit_cast(s16x2, m), acc, false);
#else
  acc = fmaf(lof(h), lof(m), acc);
  return fmaf(hif(h), hif(m), acc);
#endif
}

// fast tanh: 1 - 2/(e^{2x}+1) via v_exp_f32 + v_rcp_f32; |rel err| ~1e-6.
__device__ __forceinline__ float fast_tanh(float x) {
  float cx = fminf(fmaxf(x, -15.f), 15.f);
  float e = __builtin_amdgcn_exp2f(cx * 2.8853900817779268f);  // e^{2x}
  return 1.f - 2.f * __builtin_amdgcn_rcpf(e + 1.f);
}

// 64B cache-bypassing reload (rare stale-L2 fallback; one RTT for the wave)
__device__ __forceinline__ void load4_b128_bypass(const uint32_t* p, uint4& a, uint4& b,
                                                  uint4& c, uint4& d) {
  asm volatile("global_load_dwordx4 %0, %4, off sc0 sc1\n\t"
               "global_load_dwordx4 %1, %5, off sc0 sc1\n\t"
               "global_load_dwordx4 %2, %6, off sc0 sc1\n\t"
               "global_load_dwordx4 %3, %7, off sc0 sc1\n\t"
               "s_waitcnt vmcnt(0)"
               : "=&v"(a), "=&v"(b), "=&v"(c), "=&v"(d)
               : "v"(p), "v"(p + 4), "v"(p + 8), "v"(p + 12)
               : "memory");
}

// ---------------- small utility kernels ----------------

__global__ void cvt_bf16_kernel(const float* __restrict__ in, ushort* __restrict__ out, int n) {
  int i = blockIdx.x * blockDim.x + threadIdx.x;
  int stride = gridDim.x * blockDim.x;
  for (; i < n; i += stride) out[i] = f2bf(in[i]);
}

// out[C][R] = (bf16) in[R][C]
__global__ void transpose_cvt_kernel(const float* __restrict__ in, ushort* __restrict__ out,
                                     int R, int C) {
  __shared__ float tile[32][33];
  int bx = blockIdx.x, by = blockIdx.y;
  int tx = threadIdx.x, ty = threadIdx.y;  // 32 x 8
#pragma unroll
  for (int yy = 0; yy < 4; ++yy) {
    long r = (long)by * 32 + ty + yy * 8;
    long c = (long)bx * 32 + tx;
    tile[ty + yy * 8][tx] = in[r * C + c];
  }
  __syncthreads();
#pragma unroll
  for (int yy = 0; yy < 4; ++yy) {
    long c = (long)bx * 32 + ty + yy * 8;  // out row
    long r = (long)by * 32 + tx;           // out col
    out[c * R + r] = f2bf(tile[tx][ty + yy * 8]);
  }
}

// biasDH[j] = f_b1[j] + sum_k f_b2[k] * f_w1[k][j]
__global__ void bias_dh_kernel(const float* __restrict__ fw1, const float* __restrict__ fb1,
                               const float* __restrict__ fb2, float* __restrict__ biasDH) {
  int j = blockIdx.x * blockDim.x + threadIdx.x;
  float s = fb1[j];
  for (int k = 0; k < NX; ++k) s += fb2[k] * fw1[(long)k * HID + j];
  biasDH[j] = s;
}

// z_0[j] = f_b1[j] + u0 @ W1u[:,j] + x0 @ W1x[:,j]; h_0 = tanh(z_0)
// Publish h_0 into DH row 0 + tagged ring slot 0 (tag 0) + sentinel slot 0 (value 0).
__global__ void fixup_row0_kernel(const float* __restrict__ fw1, const float* __restrict__ fb1,
                                  const float* __restrict__ u, const float* __restrict__ x0,
                                  ushort* __restrict__ DH, uint32_t* __restrict__ HTAG,
                                  uint32_t* __restrict__ SENT) {
  int j = blockIdx.x * blockDim.x + threadIdx.x;
  float s = fb1[j];
  for (int k = 0; k < NU; ++k) s += u[k] * fw1[(long)(NX + k) * HID + j];
  for (int k = 0; k < NX; ++k) s += x0[k] * fw1[(long)k * HID + j];
  float h = tanhf(s);
  ushort hb = f2bf(h);
  DH[j] = hb;
  HTAG[j] = ((uint32_t)hb << 16);     // tag = 0
  if (j < SEQ_WGS) SENT[j << 4] = 0;  // sentinel slot 0, value = step 0
}

__global__ void x0_row_kernel(const float* __restrict__ x0, ushort* __restrict__ X) {
  int j = blockIdx.x * blockDim.x + threadIdx.x;
  if (j < NX) X[j] = f2bf(x0[j]);
}

// ---------------- generic bf16 MFMA GEMM ----------------
#define GBM 128
#define GBN 128
#define GBK 32
#define LDT 40

__global__ __launch_bounds__(256) void gemm_kernel(
    const ushort* __restrict__ A, const ushort* __restrict__ BT,
    void* __restrict__ Cout, const float* __restrict__ bias,
    int M, int N, int K, int flags)
{
  __shared__ ushort Al[GBM * LDT];
  __shared__ ushort Bl[GBN * LDT];
  const int tid = threadIdx.x;
  const int bm = blockIdx.y, bn = blockIdx.x;
  const int wave = tid >> 6, lane = tid & 63;
  const int wr = wave >> 1, wc = wave & 1;
  const int l15 = lane & 15, l4 = lane >> 4;

  f32x4 acc[4][4];
#pragma unroll
  for (int m = 0; m < 4; ++m)
#pragma unroll
    for (int n = 0; n < 4; ++n) acc[m][n] = (f32x4){0.f, 0.f, 0.f, 0.f};

  const int r_t = tid >> 1;
  const int h_t = (tid & 1) * 16;
  const long arow = (long)bm * GBM + r_t;
  const long brow = (long)bn * GBN + r_t;

  for (int k0 = 0; k0 < K; k0 += GBK) {
    uint4 a0 = make_uint4(0,0,0,0), a1 = make_uint4(0,0,0,0);
    if (arow < M) {
      const ushort* p = A + arow * K + k0 + h_t;
      a0 = *(const uint4*)p;
      a1 = *(const uint4*)(p + 8);
    }
    const ushort* q = BT + brow * K + k0 + h_t;
    uint4 b0 = *(const uint4*)q;
    uint4 b1 = *(const uint4*)(q + 8);
    __syncthreads();
    *(uint4*)&Al[r_t * LDT + h_t]     = a0;
    *(uint4*)&Al[r_t * LDT + h_t + 8] = a1;
    *(uint4*)&Bl[r_t * LDT + h_t]     = b0;
    *(uint4*)&Bl[r_t * LDT + h_t + 8] = b1;
    __syncthreads();

    bf16x8 af[4], bfv[4];
#pragma unroll
    for (int m = 0; m < 4; ++m)
      af[m] = *(const bf16x8*)&Al[(wr * 64 + m * 16 + l15) * LDT + l4 * 8];
#pragma unroll
    for (int n = 0; n < 4; ++n)
      bfv[n] = *(const bf16x8*)&Bl[(wc * 64 + n * 16 + l15) * LDT + l4 * 8];
#pragma unroll
    for (int m = 0; m < 4; ++m)
#pragma unroll
      for (int n = 0; n < 4; ++n)
        acc[m][n] = __builtin_amdgcn_mfma_f32_16x16x32_bf16(af[m], bfv[n], acc[m][n], 0, 0, 0);
  }

  const bool f32out = (flags & 2) != 0;
  const bool dotanh = (flags & 1) != 0;
#pragma unroll
  for (int m = 0; m < 4; ++m) {
#pragma unroll
    for (int n = 0; n < 4; ++n) {
#pragma unroll
      for (int j = 0; j < 4; ++j) {
        long grow = (long)bm * GBM + wr * 64 + m * 16 + l4 * 4 + j;
        int  gcol = bn * GBN + wc * 64 + n * 16 + l15;
        if (grow < M) {
          float v = acc[m][n][j];
          if (bias) v += bias[gcol];
          if (dotanh) v = tanhf(v);
          if (f32out) ((float*)Cout)[grow * N + gcol] = v;
          else        ((ushort*)Cout)[grow * N + gcol] = f2bf(v);
        }
      }
    }
  }
}

// ---------------- persistent sequential kernel (drained-producer sentinel) ----------
// h_{i+1} = tanh(h_i @ M + D[i+1]).  Data ring HTAG[RING][HID]: word =
// (bf16(h)<<16)|(step&0xffff).  Sentinel ring SENT[RING][256 lines]: one 64B line
// per producer WG, value = step index of the row.
//
// Producer protocol (end of iteration i, publishing row i+1):
//   each wave lane0: agent-store u64 data word; plain DH store;
//                    s_waitcnt vmcnt(0)  (drain to coherence point);
//                    LDS pflag[w] = i (release).
//   wave 7 lane0:    wait all 8 pflags == i, then agent-store sentinel = i+1.
// => sentinel visible  =>  the WG's whole 64B data line is fresh at the MALL.
//
// Consumer (iteration i): thread t<256 polls producer t's sentinel (agent atomic);
// on fresh, fetches its 64B line with PLAIN CACHED dwordx4 (cold line -> one MALL
// fill per XCD, shared by the 32 co-located WGs); verifies the 16 embedded tags
// (stale-L2 hit => wave-wide sc0sc1 bypass retry); packs+stages to double-buffered
// LDS. ONE __syncthreads, then all 512 threads dot from LDS (M register-resident,
// v_dot2_f32_bf16). 0xAA poison (tag 0xAAAA, sentinel 0xAAAAAAAA) matches nothing.
// hl[2] parity + the barrier make stage(i+2) impossible before dot(i) completes.
__global__ __launch_bounds__(SEQ_BLK, 1) void seq_kernel(
    const ushort* __restrict__ MT, ushort* __restrict__ DH,
    uint32_t* __restrict__ HTAG, uint32_t* __restrict__ SENT, int nsteps)
{
  __shared__ ushort hl[2][HID];   // 16 KB double-buffered h staging
  __shared__ int pflag[8];        // producer drain flags (step-valued)

  const int tid = threadIdx.x;
  const int w = tid >> 6;                        // wave 0..7
  const int lane = tid & 63;
  const int c0 = (blockIdx.x << 4) + (w << 1);   // this wave's first output column
  const int myWG = blockIdx.x;

  // M fragments: packed bf16, 2 columns x 8 uint4 = 64 VGPRs.
  // m{A,B}[j] covers k in [512j + 8*lane, 512j + 8*lane + 8).
  uint4 mA[8], mB[8];
  {
    const uint4* rA = (const uint4*)(MT + (size_t)c0 * HID);
    const uint4* rB = (const uint4*)(MT + (size_t)(c0 + 1) * HID);
#pragma unroll
    for (int j = 0; j < 8; ++j) {
      mA[j] = rA[lane + 64 * j];
      mB[j] = rB[lane + 64 * j];
    }
  }

  if (tid < 8) pflag[tid] = -1;
  __syncthreads();

  const bool prod = (lane == 0);

  for (int i = 0; i < nsteps; ++i) {
    const uint32_t tg = (uint32_t)i & 0xffffu;
    const int slot = i & (RING - 1);
    uint32_t* rowp = HTAG + (size_t)slot * HID;
    const int buf = i & 1;

    // Prefetch D_{i+1} for both columns (own dword; read before the overwrite below).
    float dA = 0.f, dB = 0.f;
    if (prod) {
      uint32_t dw = *(const uint32_t*)(DH + (size_t)(i + 1) * HID + c0);
      dA = lof(dw); dB = hif(dw);
    }

    // ---- per-line: poll sentinel -> cached fetch -> verify -> stage ----
    if (tid < SEQ_WGS) {
      uint32_t* sp = SENT + ((size_t)slot << 12) + (tid << 4);
      while (__hip_atomic_load(sp, __ATOMIC_RELAXED, __HIP_MEMORY_SCOPE_AGENT)
             != (uint32_t)i)
        __builtin_amdgcn_s_sleep(1);
      asm volatile("" ::: "memory");   // keep the fetch below the spin

      const uint4* cp = (const uint4*)(rowp + (tid << 4));
      uint4 v0 = cp[0], v1 = cp[1], v2 = cp[2], v3 = cp[3];
      uint32_t bad = ((v0.x^tg)|(v0.y^tg)|(v0.z^tg)|(v0.w^tg)|
                      (v1.x^tg)|(v1.y^tg)|(v1.z^tg)|(v1.w^tg)|
                      (v2.x^tg)|(v2.y^tg)|(v2.z^tg)|(v2.w^tg)|
                      (v3.x^tg)|(v3.y^tg)|(v3.z^tg)|(v3.w^tg)) & 0xffffu;
      if (__builtin_expect(bad != 0, 0)) {
        // stale L2 line (ring reuse) — wave-wide bypass reload, one RTT
        const uint32_t* wp = rowp + (tid << 4);
        do {
          load4_b128_bypass(wp, v0, v1, v2, v3);
          bad = ((v0.x^tg)|(v0.y^tg)|(v0.z^tg)|(v0.w^tg)|
                 (v1.x^tg)|(v1.y^tg)|(v1.z^tg)|(v1.w^tg)|
                 (v2.x^tg)|(v2.y^tg)|(v2.z^tg)|(v2.w^tg)|
                 (v3.x^tg)|(v3.y^tg)|(v3.z^tg)|(v3.w^tg)) & 0xffffu;
          if (bad) __builtin_amdgcn_s_sleep(1);
        } while (bad);
      }

      uint4 pk0, pk1;
      pk0.x = (v0.x >> 16) | (v0.y & 0xffff0000u);
      pk0.y = (v0.z >> 16) | (v0.w & 0xffff0000u);
      pk0.z = (v1.x >> 16) | (v1.y & 0xffff0000u);
      pk0.w = (v1.z >> 16) | (v1.w & 0xffff0000u);
      pk1.x = (v2.x >> 16) | (v2.y & 0xffff0000u);
      pk1.y = (v2.z >> 16) | (v2.w & 0xffff0000u);
      pk1.z = (v3.x >> 16) | (v3.y & 0xffff0000u);
      pk1.w = (v3.z >> 16) | (v3.w & 0xffff0000u);
      ((uint4*)hl[buf])[2 * tid]     = pk0;
      ((uint4*)hl[buf])[2 * tid + 1] = pk1;
    }
    __syncthreads();

    // ---- dot over this lane's k-slice for both columns ----
    float accA = 0.f, accB = 0.f;
    const uint4* h4 = (const uint4*)hl[buf];
#pragma unroll
    for (int j = 0; j < 8; ++j) {
      uint4 hv = h4[lane + 64 * j];
      accA = dot2bf(hv.x, mA[j].x, accA);  accB = dot2bf(hv.x, mB[j].x, accB);
      accA = dot2bf(hv.y, mA[j].y, accA);  accB = dot2bf(hv.y, mB[j].y, accB);
      accA = dot2bf(hv.z, mA[j].z, accA);  accB = dot2bf(hv.z, mB[j].z, accB);
      accA = dot2bf(hv.w, mA[j].w, accA);  accB = dot2bf(hv.w, mB[j].w, accB);
    }
    // dual reduce: fold halves, butterfly within halves, fetch B total to lane0
    accA += __shfl_xor(accA, 32, 64);
    accB += __shfl_xor(accB, 32, 64);
    float y = (lane < 32) ? accA : accB;
#pragma unroll
    for (int off = 16; off >= 1; off >>= 1)
      y += __shfl_xor(y, off, 64);
    float totB = __shfl(y, 32, 64);

    // ---- publish row i+1 (drained-producer protocol) ----
    if (prod) {
      ushort ha = f2bf(fast_tanh(y + dA));
      ushort hb = f2bf(fast_tanh(totB + dB));
      uint32_t tg1 = (uint32_t)(i + 1) & 0xffffu;
      unsigned long long word =
          ((unsigned long long)(((uint32_t)hb << 16) | tg1) << 32) |
          (unsigned long long)(((uint32_t)ha << 16) | tg1);
      unsigned long long* dst =
          (unsigned long long*)(HTAG + (size_t)((i + 1) & (RING - 1)) * HID) + (c0 >> 1);
      __hip_atomic_store(dst, word, __ATOMIC_RELAXED, __HIP_MEMORY_SCOPE_AGENT);
      *(uint32_t*)(DH + (size_t)(i + 1) * HID + c0) = (uint32_t)ha | ((uint32_t)hb << 16);
      asm volatile("s_waitcnt vmcnt(0)" ::: "memory");   // drain to coherence point
      __hip_atomic_store(&pflag[w], i, __ATOMIC_RELEASE, __HIP_MEMORY_SCOPE_WORKGROUP);
      if (w == 7) {
#pragma unroll
        for (int j = 0; j < 8; ++j)
          while (__hip_atomic_load(&pflag[j], __ATOMIC_ACQUIRE,
                                   __HIP_MEMORY_SCOPE_WORKGROUP) < i) { }
        __hip_atomic_store(SENT + ((size_t)((i + 1) & (RING - 1)) << 12) + (myWG << 4),
                           (uint32_t)(i + 1), __ATOMIC_RELAXED, __HIP_MEMORY_SCOPE_AGENT);
      }
    }
  }
}

// ---------------- launch ----------------

extern "C" void kernel_launch(void* const* d_in, const int* in_sizes, int n_in,
                              void* d_out, int out_size, void* d_ws, size_t ws_size,
                              hipStream_t stream) {
  const float* x0  = (const float*)d_in[0];
  const float* u   = (const float*)d_in[1];
  const float* fw1 = (const float*)d_in[2];
  const float* fb1 = (const float*)d_in[3];
  const float* fw2 = (const float*)d_in[4];
  const float* fb2 = (const float*)d_in[5];
  const float* gw1 = (const float*)d_in[6];
  const float* gb1 = (const float*)d_in[7];
  const float* gw2 = (const float*)d_in[8];
  const float* gb2 = (const float*)d_in[9];
  float* out = (float*)d_out;

  char* ws = (char*)d_ws;
  size_t off = 0;
  auto alloc = [&](size_t bytes) -> char* {
    char* p = ws + off; off += (bytes + 255) & ~(size_t)255; return p;
  };
  ushort* MT     = (ushort*)alloc((size_t)HID * HID * 2);
  ushort* DH     = (ushort*)alloc((size_t)T_STEPS * HID * 2);
  ushort* X      = (ushort*)alloc((size_t)T_STEPS * NX * 2);
  ushort* W1xT   = (ushort*)alloc((size_t)HID * NX * 2);
  ushort* W1uT   = (ushort*)alloc((size_t)HID * NU * 2);
  ushort* W2bf   = (ushort*)alloc((size_t)HID * NX * 2);
  ushort* W2T    = (ushort*)alloc((size_t)NX * HID * 2);
  ushort* Gw1T   = (ushort*)alloc((size_t)HID * NX * 2);
  ushort* Gw2T   = (ushort*)alloc((size_t)NY * HID * 2);
  ushort* Ubf    = (ushort*)alloc((size_t)T_STEPS * NU * 2);
  float*  biasDH = (float*)alloc((size_t)HID * 4);
  uint32_t* HTAG = (uint32_t*)alloc((size_t)RING * HID * 4);
  uint32_t* SENT = (uint32_t*)alloc((size_t)RING * 4096 * 4);  // [RING][256 lines of 16 u32]
  if (off > ws_size) return;  // workspace too small; bail

  cvt_bf16_kernel<<<2048, 256, 0, stream>>>(u, Ubf, T_STEPS * NU);
  cvt_bf16_kernel<<<2048, 256, 0, stream>>>(fw2, W2bf, HID * NX);
  transpose_cvt_kernel<<<dim3(HID/32, NX/32), dim3(32, 8), 0, stream>>>(fw1, W1xT, NX, HID);
  transpose_cvt_kernel<<<dim3(HID/32, NU/32), dim3(32, 8), 0, stream>>>(fw1 + (size_t)NX * HID, W1uT, NU, HID);
  transpose_cvt_kernel<<<dim3(NX/32, HID/32), dim3(32, 8), 0, stream>>>(fw2, W2T, HID, NX);
  transpose_cvt_kernel<<<dim3(HID/32, NX/32), dim3(32, 8), 0, stream>>>(gw1, Gw1T, NX, HID);
  transpose_cvt_kernel<<<dim3(NY/32, HID/32), dim3(32, 8), 0, stream>>>(gw2, Gw2T, HID, NY);
  bias_dh_kernel<<<HID/256, 256, 0, stream>>>(fw1, fb1, fb2, biasDH);

  // MT[j][k] = M[k][j] = sum_p W2[k][p] * W1x[p][j]
  gemm_kernel<<<dim3(HID/128, HID/128), 256, 0, stream>>>(W1xT, W2bf, MT, nullptr, HID, HID, NX, 0);
  // DH = Ubf @ W1u + (b1 + b2@W1x)
  gemm_kernel<<<dim3(HID/128, T_STEPS/128), 256, 0, stream>>>(Ubf, W1uT, DH, biasDH, T_STEPS, HID, NU, 0);
  // h_0 into DH row 0 + tagged ring slot 0 + sentinel slot 0
  fixup_row0_kernel<<<HID/256, 256, 0, stream>>>(fw1, fb1, u, x0, DH, HTAG, SENT);

  // sequential recurrence: h_{i+1} = tanh(h_i @ M + D[i+1]), i = 0..8189
  {
    int nsteps = T_STEPS - 2;  // produce h_1 .. h_8190
    void* MT_p = (void*)MT; void* DH_p = (void*)DH;
    void* ht_p = (void*)HTAG; void* se_p = (void*)SENT;
    void* args[] = { &MT_p, &DH_p, &ht_p, &se_p, &nsteps };
    hipError_t e = hipLaunchCooperativeKernel((const void*)seq_kernel, dim3(SEQ_WGS),
                                              dim3(SEQ_BLK), args, 0, stream);
    if (e != hipSuccess) {
      (void)hipGetLastError();
      seq_kernel<<<SEQ_WGS, SEQ_BLK, 0, stream>>>(MT, DH, HTAG, SENT, nsteps);
    }
  }

  x0_row_kernel<<<NX/256, 256, 0, stream>>>(x0, X);
  // X[1..8191] = H[0..8190] @ W2 + b2
  gemm_kernel<<<dim3(NX/128, T_STEPS/128), 256, 0, stream>>>(DH, W2T, X + NX, fb2, T_STEPS - 1, NX, HID, 0);
  // G = tanh(X @ g_w1 + g_b1) -> reuse DH buffer
  gemm_kernel<<<dim3(HID/128, T_STEPS/128), 256, 0, stream>>>(X, Gw1T, DH, gb1, T_STEPS, HID, NX, 1);
  // Y = G @ g_w2 + g_b2 -> fp32 out
  gemm_kernel<<<dim3(NY/128, T_STEPS/128), 256, 0, stream>>>(DH, Gw2T, out, gb2, T_STEPS, NY, HID, 2);
}